// Round 1
// baseline (1110.993 us; speedup 1.0000x reference)
//
#include <hip/hip_runtime.h>
#include <hip/hip_bf16.h>
#include <math.h>

#define B2    2048
#define NPM   30
#define EPM   120
#define HDIM  128
#define INDIM 74

// ---------------------------------------------------------------------------
// 4x4 micro-tile FMA helper
// ---------------------------------------------------------------------------
__device__ __forceinline__ void fma44(float (&acc)[4][4], const float4 a, const float4 w) {
  acc[0][0] = fmaf(a.x, w.x, acc[0][0]); acc[0][1] = fmaf(a.x, w.y, acc[0][1]);
  acc[0][2] = fmaf(a.x, w.z, acc[0][2]); acc[0][3] = fmaf(a.x, w.w, acc[0][3]);
  acc[1][0] = fmaf(a.y, w.x, acc[1][0]); acc[1][1] = fmaf(a.y, w.y, acc[1][1]);
  acc[1][2] = fmaf(a.y, w.z, acc[1][2]); acc[1][3] = fmaf(a.y, w.w, acc[1][3]);
  acc[2][0] = fmaf(a.z, w.x, acc[2][0]); acc[2][1] = fmaf(a.z, w.y, acc[2][1]);
  acc[2][2] = fmaf(a.z, w.z, acc[2][2]); acc[2][3] = fmaf(a.z, w.w, acc[2][3]);
  acc[3][0] = fmaf(a.w, w.x, acc[3][0]); acc[3][1] = fmaf(a.w, w.y, acc[3][1]);
  acc[3][2] = fmaf(a.w, w.z, acc[3][2]); acc[3][3] = fmaf(a.w, w.w, acc[3][3]);
}

// ---------------------------------------------------------------------------
// Per-molecule GraphConv x2 + mean pool.  grid = 2 graphs * 2048 molecules.
// ---------------------------------------------------------------------------
__global__ __launch_bounds__(256) void gc_kernel(
    const float* __restrict__ h1, const float* __restrict__ h2,
    const int* __restrict__ src1, const int* __restrict__ dst1,
    const int* __restrict__ src2, const int* __restrict__ dst2,
    const float* __restrict__ Wg1, const float* __restrict__ bg1,
    const float* __restrict__ Wg2, const float* __restrict__ bg2,
    const float* __restrict__ solv1x, float* __restrict__ xcat)
{
  const int bid = blockIdx.x;
  const int g   = bid >> 11;       // graph 0/1
  const int m   = bid & 2047;      // molecule
  const int tid = threadIdx.x;
  const float* hsrc = g ? h2 : h1;
  const int*   src  = g ? src2 : src1;
  const int*   dst  = g ? dst2 : dst1;

  __shared__ int   esrc[EPM], edst[EPM];
  __shared__ int   degO[NPM], degI[NPM];
  __shared__ float rsO[NPM], rsI[NPM];
  __shared__ float PA[128 * 36];     // transposed [d][r] matrix (At / a2t)
  __shared__ float PB[NPM * 128];    // agg buffers (stride 76 layer1, 128 layer2)
  __shared__ float XB[NPM * 76];     // scaled input
  __shared__ float TB[32 * 128];     // t1 then t2
  __shared__ float WS[128 * 128];    // staged weight

  if (tid < NPM) { degO[tid] = 0; degI[tid] = 0; }
  __syncthreads();
  if (tid < EPM) {
    int s = src[m * EPM + tid] - m * NPM;
    int d = dst[m * EPM + tid] - m * NPM;
    esrc[tid] = s; edst[tid] = d;
    atomicAdd(&degO[s], 1); atomicAdd(&degI[d], 1);
  }
  __syncthreads();
  if (tid < NPM) {
    rsO[tid] = 1.0f / sqrtf((float)max(degO[tid], 1));
    rsI[tid] = 1.0f / sqrtf((float)max(degI[tid], 1));
  }
  for (int i = tid; i < NPM * 76; i += 256) PB[i] = 0.f;
  __syncthreads();
  // stage x * rsqrt(d_out)
  for (int i = tid; i < NPM * INDIM; i += 256) {
    int r = i / INDIM, c = i - r * INDIM;
    XB[r * 76 + c] = hsrc[(m * NPM + r) * INDIM + c] * rsO[r];
  }
  __syncthreads();
  // scatter layer 1
  for (int i = tid; i < EPM * INDIM; i += 256) {
    int e = i / INDIM, c = i - e * INDIM;
    atomicAdd(&PB[edst[e] * 76 + c], XB[esrc[e] * 76 + c]);
  }
  __syncthreads();
  // transpose + rsqrt(d_in) scale  ->  PA[d][r], d<74, 32 rows (30 real + 2 zero)
  for (int i = tid; i < INDIM * 32; i += 256) {
    int d = i >> 5, r = i & 31;
    PA[d * 36 + r] = (r < NPM) ? PB[r * 76 + d] * rsI[r] : 0.f;
  }
  // stage Wg1 (74 x 128)
  for (int i = tid; i < INDIM * 32; i += 256) {
    int d = i >> 5, c4 = (i & 31) << 2;
    *(float4*)&WS[d * 128 + c4] = *(const float4*)&Wg1[d * 128 + c4];
  }
  __syncthreads();
  // GEMM1: (32x74)@(74x128)+bg1, relu -> TB
  {
    const int rgrp = tid >> 5, cgrp = tid & 31;
    const int r0 = rgrp * 4, c0 = cgrp * 4;
    float acc[4][4];
    float4 bv = *(const float4*)&bg1[c0];
    for (int i = 0; i < 4; ++i) { acc[i][0] = bv.x; acc[i][1] = bv.y; acc[i][2] = bv.z; acc[i][3] = bv.w; }
    #pragma unroll 2
    for (int d = 0; d < INDIM; ++d) {
      float4 a = *(const float4*)&PA[d * 36 + r0];
      float4 w = *(const float4*)&WS[d * 128 + c0];
      fma44(acc, a, w);
    }
    for (int i = 0; i < 4; ++i) {
      float4 o;
      o.x = fmaxf(acc[i][0], 0.f); o.y = fmaxf(acc[i][1], 0.f);
      o.z = fmaxf(acc[i][2], 0.f); o.w = fmaxf(acc[i][3], 0.f);
      *(float4*)&TB[(r0 + i) * 128 + c0] = o;
    }
  }
  __syncthreads();
  // zero layer-2 agg
  for (int i = tid; i < NPM * 128; i += 256) PB[i] = 0.f;
  __syncthreads();
  // scatter layer 2 (scale by rsO of source on the fly)
  for (int i = tid; i < EPM * 128; i += 256) {
    int e = i >> 7, c = i & 127;
    atomicAdd(&PB[edst[e] * 128 + c], TB[esrc[e] * 128 + c] * rsO[esrc[e]]);
  }
  __syncthreads();
  // transpose + scale
  for (int i = tid; i < 128 * 32; i += 256) {
    int d = i >> 5, r = i & 31;
    PA[d * 36 + r] = (r < NPM) ? PB[r * 128 + d] * rsI[r] : 0.f;
  }
  // stage Wg2 (128x128)
  for (int i = tid; i < 128 * 32; i += 256) {
    int d = i >> 5, c4 = (i & 31) << 2;
    *(float4*)&WS[d * 128 + c4] = *(const float4*)&Wg2[d * 128 + c4];
  }
  __syncthreads();
  // GEMM2: (32x128)@(128x128)+bg2, relu -> TB
  {
    const int rgrp = tid >> 5, cgrp = tid & 31;
    const int r0 = rgrp * 4, c0 = cgrp * 4;
    float acc[4][4];
    float4 bv = *(const float4*)&bg2[c0];
    for (int i = 0; i < 4; ++i) { acc[i][0] = bv.x; acc[i][1] = bv.y; acc[i][2] = bv.z; acc[i][3] = bv.w; }
    #pragma unroll 4
    for (int d = 0; d < 128; ++d) {
      float4 a = *(const float4*)&PA[d * 36 + r0];
      float4 w = *(const float4*)&WS[d * 128 + c0];
      fma44(acc, a, w);
    }
    for (int i = 0; i < 4; ++i) {
      float4 o;
      o.x = fmaxf(acc[i][0], 0.f); o.y = fmaxf(acc[i][1], 0.f);
      o.z = fmaxf(acc[i][2], 0.f); o.w = fmaxf(acc[i][3], 0.f);
      *(float4*)&TB[(r0 + i) * 128 + c0] = o;
    }
  }
  __syncthreads();
  // mean over 30 nodes * solv factor
  if (tid < 128) {
    float s = 0.f;
    for (int r = 0; r < NPM; ++r) s += TB[r * 128 + tid];
    float sf = g ? (1.f - solv1x[m]) : solv1x[m];
    xcat[(g * B2 + m) * 128 + tid] = s * (1.f / 30.f) * sf;
  }
}

// ---------------------------------------------------------------------------
// Generic fp32 GEMM: C = [relu]( A(MxK) @ W(KxN) [+ bias] ).  64x64 tile.
// ---------------------------------------------------------------------------
template<int RELU, int BIAS>
__global__ __launch_bounds__(256) void gemm_kernel(
    const float* __restrict__ A, const float* __restrict__ W,
    const float* __restrict__ bias, float* __restrict__ C,
    int M, int Ncols, int K)
{
  __shared__ float At[64 * 64];   // [d][r]
  __shared__ float Ws[64 * 64];   // [d][c]
  const int tid = threadIdx.x;
  const int rowBase = blockIdx.x * 64, colBase = blockIdx.y * 64;
  const int rgrp = tid >> 4, cgrp = tid & 15;
  const int r0 = rgrp * 4, c0 = cgrp * 4;
  float acc[4][4] = {{0.f}};
  for (int k0 = 0; k0 < K; k0 += 64) {
    for (int t = tid; t < 1024; t += 256) {
      int row = t & 63, kk = (t >> 6) << 2;
      float4 v = *(const float4*)&A[(rowBase + row) * K + k0 + kk];
      At[(kk + 0) * 64 + row] = v.x; At[(kk + 1) * 64 + row] = v.y;
      At[(kk + 2) * 64 + row] = v.z; At[(kk + 3) * 64 + row] = v.w;
    }
    for (int t = tid; t < 1024; t += 256) {
      int d = t >> 4, c4 = (t & 15) << 2;
      *(float4*)&Ws[d * 64 + c4] = *(const float4*)&W[(k0 + d) * Ncols + colBase + c4];
    }
    __syncthreads();
    #pragma unroll 8
    for (int d = 0; d < 64; ++d) {
      float4 a = *(const float4*)&At[d * 64 + r0];
      float4 w = *(const float4*)&Ws[d * 64 + c0];
      fma44(acc, a, w);
    }
    __syncthreads();
  }
  float4 bv = make_float4(0.f, 0.f, 0.f, 0.f);
  if (BIAS) bv = *(const float4*)&bias[colBase + c0];
  for (int i = 0; i < 4; ++i) {
    float4 o;
    o.x = acc[i][0] + bv.x; o.y = acc[i][1] + bv.y;
    o.z = acc[i][2] + bv.z; o.w = acc[i][3] + bv.w;
    if (RELU) { o.x = fmaxf(o.x, 0.f); o.y = fmaxf(o.y, 0.f); o.z = fmaxf(o.z, 0.f); o.w = fmaxf(o.w, 0.f); }
    *(float4*)&C[(rowBase + r0 + i) * Ncols + colBase + c0] = o;
  }
}

// ---------------------------------------------------------------------------
// Edge MLP first layer: eh = relu(ef * We1 + be1) for the 3 scalar-per-mixture
// edge features. grid covers 2048*32.
// ---------------------------------------------------------------------------
__global__ __launch_bounds__(256) void eh_kernel(
    const float* __restrict__ interhb, const float* __restrict__ ia1,
    const float* __restrict__ ia2, const float* __restrict__ We1,
    const float* __restrict__ be1,
    float* __restrict__ ehI, float* __restrict__ ehA, float* __restrict__ ehB)
{
  int idx = blockIdx.x * 256 + threadIdx.x;        // 2048*32
  int i = idx >> 5, k = idx & 31;
  float a = We1[k], b = be1[k];
  ehI[idx] = fmaxf(fmaf(interhb[i], a, b), 0.f);
  ehA[idx] = fmaxf(fmaf(ia1[i],     a, b), 0.f);
  ehB[idx] = fmaxf(fmaf(ia2[i],     a, b), 0.f);
}

// ---------------------------------------------------------------------------
// Fused z-GEMM + eh-fold.  z[n,k,f] = sum_d xp[n,d]*We2[k,d,f], folded against
// eh weights into agg contributions (never materialized).
// grid = 128 mixture-groups (16 mixtures) * 2 k-halves.
// ---------------------------------------------------------------------------
__global__ __launch_bounds__(256) void zfold_kernel(
    const float* __restrict__ xp, const float* __restrict__ We2,
    const float* __restrict__ ehI, const float* __restrict__ ehA,
    const float* __restrict__ ehB,
    float* __restrict__ aggA, float* __restrict__ aggB)
{
  __shared__ float xsT[128 * 36];          // [d][row], 32 rows
  __shared__ float Ws[64 * 128];           // half of We2_k
  __shared__ float ehs[3][16][32];         // inter / intra1 / intra2
  __shared__ float accAs[16 * 128], accBs[16 * 128];
  const int tid = threadIdx.x;
  const int mg = blockIdx.x >> 1, kh = blockIdx.x & 1;
  const int i0 = mg * 16;

  for (int t = tid; t < 1024; t += 256) {
    int row = t & 31, d4 = t >> 5;
    int gr = (row < 16) ? (i0 + row) : (B2 + i0 + row - 16);
    float4 v = *(const float4*)&xp[gr * 128 + d4 * 4];
    xsT[(d4 * 4 + 0) * 36 + row] = v.x; xsT[(d4 * 4 + 1) * 36 + row] = v.y;
    xsT[(d4 * 4 + 2) * 36 + row] = v.z; xsT[(d4 * 4 + 3) * 36 + row] = v.w;
  }
  for (int t = tid; t < 512; t += 256) {
    int mm = t >> 5, k = t & 31;
    ehs[0][mm][k] = ehI[(i0 + mm) * 32 + k];
    ehs[1][mm][k] = ehA[(i0 + mm) * 32 + k];
    ehs[2][mm][k] = ehB[(i0 + mm) * 32 + k];
  }
  for (int t = tid; t < 16 * 128; t += 256) { accAs[t] = 0.f; accBs[t] = 0.f; }

  const int rgrp = tid >> 5, cgrp = tid & 31;
  const int r0 = rgrp * 4, c0 = cgrp * 4;
  const int side = rgrp >> 2;              // 0: rows 0..15 (i), 1: rows 16..31 (i+B)
  float accLo[4][4] = {{0.f}}, accHi[4][4] = {{0.f}};

  for (int kk = 0; kk < 16; ++kk) {
    const int k = kh * 16 + kk;
    float z[4][4] = {{0.f}};
    for (int ch = 0; ch < 2; ++ch) {
      __syncthreads();
      for (int t = tid; t < 2048; t += 256) {
        int d = t >> 5, c4 = (t & 31) << 2;
        *(float4*)&Ws[d * 128 + c4] =
            *(const float4*)&We2[k * 16384 + (ch * 64 + d) * 128 + c4];
      }
      __syncthreads();
      #pragma unroll 4
      for (int d = 0; d < 64; ++d) {
        float4 a = *(const float4*)&xsT[(ch * 64 + d) * 36 + r0];
        float4 w = *(const float4*)&Ws[d * 128 + c0];
        fma44(z, a, w);
      }
    }
    #pragma unroll
    for (int i = 0; i < 4; ++i) {
      int mm = (r0 + i) & 15;
      float uLo = side ? ehs[0][mm][k] : ehs[1][mm][k];
      float uHi = side ? ehs[2][mm][k] : ehs[0][mm][k];
      #pragma unroll
      for (int j = 0; j < 4; ++j) {
        accLo[i][j] = fmaf(uLo, z[i][j], accLo[i][j]);
        accHi[i][j] = fmaf(uHi, z[i][j], accHi[i][j]);
      }
    }
  }
  __syncthreads();
  for (int i = 0; i < 4; ++i) {
    int mm = (r0 + i) & 15;
    for (int j = 0; j < 4; ++j) {
      atomicAdd(&accAs[mm * 128 + c0 + j], accLo[i][j]);
      atomicAdd(&accBs[mm * 128 + c0 + j], accHi[i][j]);
    }
  }
  __syncthreads();
  for (int t = tid; t < 2048; t += 256) {
    int mm = t >> 7, c = t & 127;
    atomicAdd(&aggA[(i0 + mm) * 128 + c], accAs[mm * 128 + c]);
    atomicAdd(&aggB[(i0 + mm) * 128 + c], accBs[mm * 128 + c]);
  }
}

// x_in = relu(agg + zb[i] + zb[i+B] + bnn)
__global__ __launch_bounds__(256) void xin_kernel(
    const float* __restrict__ aggA, const float* __restrict__ aggB,
    const float* __restrict__ zb, const float* __restrict__ bnn,
    float* __restrict__ x_in)
{
  int idx = blockIdx.x * 256 + threadIdx.x;        // 2048*128
  int i = idx >> 7, c = idx & 127;
  float zs = zb[i * 128 + c] + zb[(i + B2) * 128 + c] + bnn[c];
  x_in[i * 128 + c]        = fmaxf(aggA[idx] + zs, 0.f);
  x_in[(i + B2) * 128 + c] = fmaxf(aggB[idx] + zs, 0.f);
}

// GRU elementwise
__global__ __launch_bounds__(256) void gru_kernel(
    const float* __restrict__ gi, const float* __restrict__ gh,
    const float* __restrict__ xp, float* __restrict__ xnew)
{
  int idx = blockIdx.x * 256 + threadIdx.x;        // 4096*128
  int n = idx >> 7, j = idx & 127;
  float ir = gi[n * 384 + j], iz = gi[n * 384 + 128 + j], ih = gi[n * 384 + 256 + j];
  float hr = gh[n * 384 + j], hz = gh[n * 384 + 128 + j], hn = gh[n * 384 + 256 + j];
  float h  = xp[idx];
  float r  = 1.f / (1.f + expf(-(ir + hr)));
  float zg = 1.f / (1.f + expf(-(iz + hz)));
  float ng = tanhf(ih + r * hn);
  xnew[idx] = (1.f - zg) * ng + zg * h;
}

// hg = [xnew[:B] | xnew[B:]]
__global__ __launch_bounds__(256) void hg_kernel(
    const float* __restrict__ xnew, float* __restrict__ hg)
{
  int idx = blockIdx.x * 256 + threadIdx.x;        // 2048*256
  int i = idx >> 8, k = idx & 255;
  hg[idx] = (k < 128) ? xnew[i * 128 + k] : xnew[(i + B2) * 128 + (k - 128)];
}

// out = o2 @ Wcl3 + bcl3   (N=2)
__global__ __launch_bounds__(256) void final_kernel(
    const float* __restrict__ o2, const float* __restrict__ Wcl3,
    const float* __restrict__ bcl3, float* __restrict__ out)
{
  int idx = blockIdx.x * 256 + threadIdx.x;        // 2048*2
  int i = idx >> 1, c = idx & 1;
  float acc = bcl3[c];
  for (int k = 0; k < 128; ++k) acc = fmaf(o2[i * 128 + k], Wcl3[k * 2 + c], acc);
  out[idx] = acc;
}

// ---------------------------------------------------------------------------
extern "C" void kernel_launch(void* const* d_in, const int* in_sizes, int n_in,
                              void* d_out, int out_size, void* d_ws, size_t ws_size,
                              hipStream_t stream)
{
  const float* h1   = (const float*)d_in[0];
  const float* h2   = (const float*)d_in[1];
  const float* s1x  = (const float*)d_in[2];
  const float* ihb  = (const float*)d_in[3];
  const float* ia1  = (const float*)d_in[4];
  const float* ia2  = (const float*)d_in[5];
  const float* Wg1  = (const float*)d_in[6];
  const float* bg1  = (const float*)d_in[7];
  const float* Wg2  = (const float*)d_in[8];
  const float* bg2  = (const float*)d_in[9];
  const float* Wp   = (const float*)d_in[10];
  const float* bp   = (const float*)d_in[11];
  const float* We1  = (const float*)d_in[12];
  const float* be1  = (const float*)d_in[13];
  const float* We2  = (const float*)d_in[14];
  const float* be2  = (const float*)d_in[15];
  const float* bnn  = (const float*)d_in[16];
  const float* Wih  = (const float*)d_in[17];
  const float* bih  = (const float*)d_in[18];
  const float* Whh  = (const float*)d_in[19];
  const float* bhh  = (const float*)d_in[20];
  const float* Wcl1 = (const float*)d_in[21];
  const float* bcl1 = (const float*)d_in[22];
  const float* Wcl2 = (const float*)d_in[23];
  const float* bcl2 = (const float*)d_in[24];
  const float* Wcl3 = (const float*)d_in[25];
  const float* bcl3 = (const float*)d_in[26];
  const int*   src1 = (const int*)d_in[27];
  const int*   dst1 = (const int*)d_in[28];
  const int*   src2 = (const int*)d_in[29];
  const int*   dst2 = (const int*)d_in[30];
  float* out = (float*)d_out;

  float* ws = (float*)d_ws;
  float* xcat = ws;                    // 4096*128
  float* xp   = ws + 524288;           // 4096*128
  float* zb   = ws + 1048576;          // 4096*128
  float* aggA = ws + 1572864;          // 2048*128
  float* aggB = ws + 1835008;          // 2048*128
  float* x_in = ws + 2097152;          // 4096*128
  float* gi   = ws + 2621440;          // 4096*384
  float* gh   = ws + 4194304;          // 4096*384
  float* xnew = ws + 5767168;          // 4096*128
  float* hg   = ws + 6291456;          // 2048*256
  float* o1   = ws + 6815744;          // 2048*128
  float* o2   = ws + 7077888;          // 2048*128
  float* ehI  = ws + 7340032;          // 2048*32
  float* ehA  = ws + 7405568;          // 2048*32
  float* ehB  = ws + 7471104;          // 2048*32

  // edge-hidden vectors
  eh_kernel<<<256, 256, 0, stream>>>(ihb, ia1, ia2, We1, be1, ehI, ehA, ehB);
  // GraphConv x2, both graphs, mean pool -> xcat (4096x128)
  gc_kernel<<<4096, 256, 0, stream>>>(h1, h2, src1, dst1, src2, dst2,
                                      Wg1, bg1, Wg2, bg2, s1x, xcat);
  // xp = relu(xcat @ Wp + bp)
  gemm_kernel<1, 1><<<dim3(64, 2), 256, 0, stream>>>(xcat, Wp, bp, xp, 4096, 128, 128);
  // zb = xp @ reshape(be2, (128,128))
  gemm_kernel<0, 0><<<dim3(64, 2), 256, 0, stream>>>(xp, be2, nullptr, zb, 4096, 128, 128);
  // zero agg accumulators, then fused z-fold
  hipMemsetAsync(aggA, 0, 2 * 262144 * sizeof(float), stream);
  zfold_kernel<<<256, 256, 0, stream>>>(xp, We2, ehI, ehA, ehB, aggA, aggB);
  xin_kernel<<<1024, 256, 0, stream>>>(aggA, aggB, zb, bnn, x_in);
  // GRU
  gemm_kernel<0, 1><<<dim3(64, 6), 256, 0, stream>>>(x_in, Wih, bih, gi, 4096, 384, 128);
  gemm_kernel<0, 1><<<dim3(64, 6), 256, 0, stream>>>(xp, Whh, bhh, gh, 4096, 384, 128);
  gru_kernel<<<2048, 256, 0, stream>>>(gi, gh, xp, xnew);
  // classifier
  hg_kernel<<<2048, 256, 0, stream>>>(xnew, hg);
  gemm_kernel<1, 1><<<dim3(32, 2), 256, 0, stream>>>(hg, Wcl1, bcl1, o1, 2048, 128, 256);
  gemm_kernel<1, 1><<<dim3(32, 2), 256, 0, stream>>>(o1, Wcl2, bcl2, o2, 2048, 128, 128);
  final_kernel<<<16, 256, 0, stream>>>(o2, Wcl3, bcl3, out);
}

// Round 2
// 830.134 us; speedup vs baseline: 1.3383x; 1.3383x over previous
//
#include <hip/hip_runtime.h>
#include <hip/hip_bf16.h>
#include <math.h>

#define B2    2048
#define NPM   30
#define EPM   120
#define HDIM  128
#define INDIM 74
#define GC_SX 34   // padded stride for transposed agg: bank=(2c+r)%32 -> <=4-way

// ---------------------------------------------------------------------------
// 4x4 micro-tile FMA helper
// ---------------------------------------------------------------------------
__device__ __forceinline__ void fma44(float (&acc)[4][4], const float4 a, const float4 w) {
  acc[0][0] = fmaf(a.x, w.x, acc[0][0]); acc[0][1] = fmaf(a.x, w.y, acc[0][1]);
  acc[0][2] = fmaf(a.x, w.z, acc[0][2]); acc[0][3] = fmaf(a.x, w.w, acc[0][3]);
  acc[1][0] = fmaf(a.y, w.x, acc[1][0]); acc[1][1] = fmaf(a.y, w.y, acc[1][1]);
  acc[1][2] = fmaf(a.y, w.z, acc[1][2]); acc[1][3] = fmaf(a.y, w.w, acc[1][3]);
  acc[2][0] = fmaf(a.z, w.x, acc[2][0]); acc[2][1] = fmaf(a.z, w.y, acc[2][1]);
  acc[2][2] = fmaf(a.z, w.z, acc[2][2]); acc[2][3] = fmaf(a.z, w.w, acc[2][3]);
  acc[3][0] = fmaf(a.w, w.x, acc[3][0]); acc[3][1] = fmaf(a.w, w.y, acc[3][1]);
  acc[3][2] = fmaf(a.w, w.z, acc[3][2]); acc[3][3] = fmaf(a.w, w.w, acc[3][3]);
}

// ---------------------------------------------------------------------------
// Per-molecule GraphConv x2 + mean pool.  grid = 2 graphs * 2048 molecules.
// LDS ~36KB -> 4 blocks/CU. W read from global (L1/L2 broadcast). Scatter
// writes directly into transposed [c][dst] layout (stride 34, <=4-way banks).
// ---------------------------------------------------------------------------
__global__ __launch_bounds__(256, 4) void gc_kernel(
    const float* __restrict__ h1, const float* __restrict__ h2,
    const int* __restrict__ src1, const int* __restrict__ dst1,
    const int* __restrict__ src2, const int* __restrict__ dst2,
    const float* __restrict__ Wg1, const float* __restrict__ bg1,
    const float* __restrict__ Wg2, const float* __restrict__ bg2,
    const float* __restrict__ solv1x, float* __restrict__ xcat)
{
  const int bid = blockIdx.x;
  const int g   = bid >> 11;       // graph 0/1
  const int m   = bid & 2047;      // molecule
  const int tid = threadIdx.x;
  const float* hsrc = g ? h2 : h1;
  const int*   src  = g ? src2 : src1;
  const int*   dst  = g ? dst2 : dst1;

  __shared__ float poolX[128 * GC_SX];  // PA1 (74 rows) then PA2 (128 rows), [c][r]
  __shared__ float poolY[4096];         // XT (30x76) then TB (30x128)
  __shared__ int   esrc[EPM], edst[EPM];
  __shared__ int   degO[32], degI[32];
  __shared__ float rsO[32], rsI[32];
  __shared__ float cs[128];

  // phase 0: zero degrees, colsum, PA1
  if (tid < 32) { degO[tid] = 0; degI[tid] = 0; }
  if (tid >= 128) cs[tid - 128] = 0.f;
  for (int i = tid; i < INDIM * GC_SX; i += 256) poolX[i] = 0.f;
  __syncthreads();
  if (tid < EPM) {
    int s = src[m * EPM + tid] - m * NPM;
    int d = dst[m * EPM + tid] - m * NPM;
    esrc[tid] = s; edst[tid] = d;
    atomicAdd(&degO[s], 1); atomicAdd(&degI[d], 1);
  }
  __syncthreads();
  if (tid < NPM) {
    rsO[tid] = rsqrtf((float)max(degO[tid], 1));
    rsI[tid] = rsqrtf((float)max(degI[tid], 1));
  }
  __syncthreads();
  // stage XT = x * rsqrt(d_out), row-major [r][76]
  for (int i = tid; i < NPM * INDIM; i += 256) {
    int r = i / INDIM, c = i - r * INDIM;
    poolY[r * 76 + c] = hsrc[m * (NPM * INDIM) + i] * rsO[r];
  }
  __syncthreads();
  // scatter layer 1 into transposed agg PA1[c][dst]
  for (int i = tid; i < EPM * INDIM; i += 256) {
    int e = i / INDIM, c = i - e * INDIM;
    atomicAdd(&poolX[c * GC_SX + edst[e]], poolY[esrc[e] * 76 + c]);
  }
  __syncthreads();
  // scale by rsqrt(d_in)
  for (int i = tid; i < INDIM * 32; i += 256) {
    int c = i >> 5, r = i & 31;
    poolX[c * GC_SX + r] *= (r < NPM) ? rsI[r] : 0.f;
  }
  __syncthreads();

  const int rgrp = tid >> 5, cgrp = tid & 31;
  const int r0 = rgrp * 4, c0 = cgrp * 4;

  // GEMM1: (32x74)@(74x128)+bg1, relu, *rsO -> TB (poolY, rows<30)
  {
    float acc[4][4];
    float4 bv = *(const float4*)&bg1[c0];
    for (int i = 0; i < 4; ++i) { acc[i][0] = bv.x; acc[i][1] = bv.y; acc[i][2] = bv.z; acc[i][3] = bv.w; }
    #pragma unroll 2
    for (int d = 0; d < INDIM; ++d) {
      float2 aLo = *(const float2*)&poolX[d * GC_SX + r0];
      float2 aHi = *(const float2*)&poolX[d * GC_SX + r0 + 2];
      float4 w   = *(const float4*)&Wg1[d * 128 + c0];
      fma44(acc, make_float4(aLo.x, aLo.y, aHi.x, aHi.y), w);
    }
    __syncthreads();   // PA1 reads done before TB overwrites XT? (TB=poolY, XT=poolY!)
    for (int i = 0; i < 4; ++i) {
      int r = r0 + i;
      if (r < NPM) {
        float s = rsO[r];
        float4 o;
        o.x = fmaxf(acc[i][0], 0.f) * s; o.y = fmaxf(acc[i][1], 0.f) * s;
        o.z = fmaxf(acc[i][2], 0.f) * s; o.w = fmaxf(acc[i][3], 0.f) * s;
        *(float4*)&poolY[r * 128 + c0] = o;
      }
    }
  }
  __syncthreads();
  // zero PA2 (full 128 rows)
  for (int i = tid; i < 128 * GC_SX; i += 256) poolX[i] = 0.f;
  __syncthreads();
  // scatter layer 2 into PA2[c][dst]
  for (int i = tid; i < EPM * HDIM; i += 256) {
    int e = i >> 7, c = i & 127;
    atomicAdd(&poolX[c * GC_SX + edst[e]], poolY[esrc[e] * 128 + c]);
  }
  __syncthreads();
  for (int i = tid; i < 128 * 32; i += 256) {
    int c = i >> 5, r = i & 31;
    poolX[c * GC_SX + r] *= (r < NPM) ? rsI[r] : 0.f;
  }
  __syncthreads();
  // GEMM2: (32x128)@(128x128)+bg2, relu, fused column-sum (mean pool)
  {
    float acc[4][4];
    float4 bv = *(const float4*)&bg2[c0];
    for (int i = 0; i < 4; ++i) { acc[i][0] = bv.x; acc[i][1] = bv.y; acc[i][2] = bv.z; acc[i][3] = bv.w; }
    #pragma unroll 4
    for (int d = 0; d < 128; ++d) {
      float2 aLo = *(const float2*)&poolX[d * GC_SX + r0];
      float2 aHi = *(const float2*)&poolX[d * GC_SX + r0 + 2];
      float4 w   = *(const float4*)&Wg2[d * 128 + c0];
      fma44(acc, make_float4(aLo.x, aLo.y, aHi.x, aHi.y), w);
    }
    float part[4] = {0.f, 0.f, 0.f, 0.f};
    for (int i = 0; i < 4; ++i) {
      if (r0 + i < NPM) {
        part[0] += fmaxf(acc[i][0], 0.f); part[1] += fmaxf(acc[i][1], 0.f);
        part[2] += fmaxf(acc[i][2], 0.f); part[3] += fmaxf(acc[i][3], 0.f);
      }
    }
    for (int j = 0; j < 4; ++j) atomicAdd(&cs[c0 + j], part[j]);
  }
  __syncthreads();
  if (tid < 128) {
    float sf = g ? (1.f - solv1x[m]) : solv1x[m];
    xcat[(g * B2 + m) * 128 + tid] = cs[tid] * (1.f / 30.f) * sf;
  }
}

// ---------------------------------------------------------------------------
// Generic fp32 GEMM: C = [relu]( A(MxK) @ W(KxN) [+ bias] ).  64x64 tile.
// ---------------------------------------------------------------------------
template<int RELU, int BIAS>
__global__ __launch_bounds__(256) void gemm_kernel(
    const float* __restrict__ A, const float* __restrict__ W,
    const float* __restrict__ bias, float* __restrict__ C,
    int M, int Ncols, int K)
{
  __shared__ float At[64 * 64];   // [d][r]
  __shared__ float Ws[64 * 64];   // [d][c]
  const int tid = threadIdx.x;
  const int rowBase = blockIdx.x * 64, colBase = blockIdx.y * 64;
  const int rgrp = tid >> 4, cgrp = tid & 15;
  const int r0 = rgrp * 4, c0 = cgrp * 4;
  float acc[4][4] = {{0.f}};
  for (int k0 = 0; k0 < K; k0 += 64) {
    for (int t = tid; t < 1024; t += 256) {
      int row = t & 63, kk = (t >> 6) << 2;
      float4 v = *(const float4*)&A[(rowBase + row) * K + k0 + kk];
      At[(kk + 0) * 64 + row] = v.x; At[(kk + 1) * 64 + row] = v.y;
      At[(kk + 2) * 64 + row] = v.z; At[(kk + 3) * 64 + row] = v.w;
    }
    for (int t = tid; t < 1024; t += 256) {
      int d = t >> 4, c4 = (t & 15) << 2;
      *(float4*)&Ws[d * 64 + c4] = *(const float4*)&W[(k0 + d) * Ncols + colBase + c4];
    }
    __syncthreads();
    #pragma unroll 8
    for (int d = 0; d < 64; ++d) {
      float4 a = *(const float4*)&At[d * 64 + r0];
      float4 w = *(const float4*)&Ws[d * 64 + c0];
      fma44(acc, a, w);
    }
    __syncthreads();
  }
  float4 bv = make_float4(0.f, 0.f, 0.f, 0.f);
  if (BIAS) bv = *(const float4*)&bias[colBase + c0];
  for (int i = 0; i < 4; ++i) {
    float4 o;
    o.x = acc[i][0] + bv.x; o.y = acc[i][1] + bv.y;
    o.z = acc[i][2] + bv.z; o.w = acc[i][3] + bv.w;
    if (RELU) { o.x = fmaxf(o.x, 0.f); o.y = fmaxf(o.y, 0.f); o.z = fmaxf(o.z, 0.f); o.w = fmaxf(o.w, 0.f); }
    *(float4*)&C[(rowBase + r0 + i) * Ncols + colBase + c0] = o;
  }
}

// ---------------------------------------------------------------------------
// Classifier layer 1 on concatenated halves: o1 = relu([x[:B]|x[B:]] @ W + b)
// M=2048, K=256, N=128; A never materialized.
// ---------------------------------------------------------------------------
__global__ __launch_bounds__(256) void gemm_cat_kernel(
    const float* __restrict__ X,      // xnew (4096 x 128)
    const float* __restrict__ W, const float* __restrict__ bias,
    float* __restrict__ C)
{
  __shared__ float At[64 * 64];
  __shared__ float Ws[64 * 64];
  const int tid = threadIdx.x;
  const int rowBase = blockIdx.x * 64, colBase = blockIdx.y * 64;
  const int rgrp = tid >> 4, cgrp = tid & 15;
  const int r0 = rgrp * 4, c0 = cgrp * 4;
  float acc[4][4] = {{0.f}};
  for (int k0 = 0; k0 < 256; k0 += 64) {
    const float* base = (k0 < 128) ? X : (X + B2 * 128);
    const int kc = k0 & 127;
    for (int t = tid; t < 1024; t += 256) {
      int row = t & 63, kk = (t >> 6) << 2;
      float4 v = *(const float4*)&base[(rowBase + row) * 128 + kc + kk];
      At[(kk + 0) * 64 + row] = v.x; At[(kk + 1) * 64 + row] = v.y;
      At[(kk + 2) * 64 + row] = v.z; At[(kk + 3) * 64 + row] = v.w;
    }
    for (int t = tid; t < 1024; t += 256) {
      int d = t >> 4, c4 = (t & 15) << 2;
      *(float4*)&Ws[d * 64 + c4] = *(const float4*)&W[(k0 + d) * 128 + colBase + c4];
    }
    __syncthreads();
    #pragma unroll 8
    for (int d = 0; d < 64; ++d) {
      float4 a = *(const float4*)&At[d * 64 + r0];
      float4 w = *(const float4*)&Ws[d * 64 + c0];
      fma44(acc, a, w);
    }
    __syncthreads();
  }
  float4 bv = *(const float4*)&bias[colBase + c0];
  for (int i = 0; i < 4; ++i) {
    float4 o;
    o.x = fmaxf(acc[i][0] + bv.x, 0.f); o.y = fmaxf(acc[i][1] + bv.y, 0.f);
    o.z = fmaxf(acc[i][2] + bv.z, 0.f); o.w = fmaxf(acc[i][3] + bv.w, 0.f);
    *(float4*)&C[(rowBase + r0 + i) * 128 + colBase + c0] = o;
  }
}

// ---------------------------------------------------------------------------
// Fused z-GEMM + eh-fold (eh MLP layer-1 computed inline).
// grid = 128 mixture-groups (16 mixtures) * 2 k-halves.
// ---------------------------------------------------------------------------
__global__ __launch_bounds__(256) void zfold_kernel(
    const float* __restrict__ xp, const float* __restrict__ We2,
    const float* __restrict__ interhb, const float* __restrict__ ia1,
    const float* __restrict__ ia2, const float* __restrict__ We1,
    const float* __restrict__ be1,
    float* __restrict__ aggA, float* __restrict__ aggB)
{
  __shared__ float xsT[128 * 36];          // [d][row], 32 rows
  __shared__ float Ws[64 * 128];           // half of We2_k
  __shared__ float ehs[3][16][32];         // inter / intra1 / intra2
  __shared__ float accAs[16 * 128], accBs[16 * 128];
  const int tid = threadIdx.x;
  const int mg = blockIdx.x >> 1, kh = blockIdx.x & 1;
  const int i0 = mg * 16;

  for (int t = tid; t < 1024; t += 256) {
    int row = t & 31, d4 = t >> 5;
    int gr = (row < 16) ? (i0 + row) : (B2 + i0 + row - 16);
    float4 v = *(const float4*)&xp[gr * 128 + d4 * 4];
    xsT[(d4 * 4 + 0) * 36 + row] = v.x; xsT[(d4 * 4 + 1) * 36 + row] = v.y;
    xsT[(d4 * 4 + 2) * 36 + row] = v.z; xsT[(d4 * 4 + 3) * 36 + row] = v.w;
  }
  for (int t = tid; t < 512; t += 256) {
    int mm = t >> 5, k = t & 31;
    float a = We1[k], b = be1[k];
    ehs[0][mm][k] = fmaxf(fmaf(interhb[i0 + mm], a, b), 0.f);
    ehs[1][mm][k] = fmaxf(fmaf(ia1[i0 + mm],     a, b), 0.f);
    ehs[2][mm][k] = fmaxf(fmaf(ia2[i0 + mm],     a, b), 0.f);
  }
  for (int t = tid; t < 16 * 128; t += 256) { accAs[t] = 0.f; accBs[t] = 0.f; }

  const int rgrp = tid >> 5, cgrp = tid & 31;
  const int r0 = rgrp * 4, c0 = cgrp * 4;
  const int side = rgrp >> 2;              // 0: rows 0..15 (i), 1: rows 16..31 (i+B)
  float accLo[4][4] = {{0.f}}, accHi[4][4] = {{0.f}};

  for (int kk = 0; kk < 16; ++kk) {
    const int k = kh * 16 + kk;
    float z[4][4] = {{0.f}};
    for (int ch = 0; ch < 2; ++ch) {
      __syncthreads();
      for (int t = tid; t < 2048; t += 256) {
        int d = t >> 5, c4 = (t & 31) << 2;
        *(float4*)&Ws[d * 128 + c4] =
            *(const float4*)&We2[k * 16384 + (ch * 64 + d) * 128 + c4];
      }
      __syncthreads();
      #pragma unroll 4
      for (int d = 0; d < 64; ++d) {
        float4 a = *(const float4*)&xsT[(ch * 64 + d) * 36 + r0];
        float4 w = *(const float4*)&Ws[d * 128 + c0];
        fma44(z, a, w);
      }
    }
    #pragma unroll
    for (int i = 0; i < 4; ++i) {
      int mm = (r0 + i) & 15;
      float uLo = side ? ehs[0][mm][k] : ehs[1][mm][k];
      float uHi = side ? ehs[2][mm][k] : ehs[0][mm][k];
      #pragma unroll
      for (int j = 0; j < 4; ++j) {
        accLo[i][j] = fmaf(uLo, z[i][j], accLo[i][j]);
        accHi[i][j] = fmaf(uHi, z[i][j], accHi[i][j]);
      }
    }
  }
  __syncthreads();
  for (int i = 0; i < 4; ++i) {
    int mm = (r0 + i) & 15;
    for (int j = 0; j < 4; ++j) {
      atomicAdd(&accAs[mm * 128 + c0 + j], accLo[i][j]);
      atomicAdd(&accBs[mm * 128 + c0 + j], accHi[i][j]);
    }
  }
  __syncthreads();
  for (int t = tid; t < 2048; t += 256) {
    int mm = t >> 7, c = t & 127;
    atomicAdd(&aggA[(i0 + mm) * 128 + c], accAs[mm * 128 + c]);
    atomicAdd(&aggB[(i0 + mm) * 128 + c], accBs[mm * 128 + c]);
  }
}

// x_in = relu(agg + zb[i] + zb[i+B] + bnn)
__global__ __launch_bounds__(256) void xin_kernel(
    const float* __restrict__ aggA, const float* __restrict__ aggB,
    const float* __restrict__ zb, const float* __restrict__ bnn,
    float* __restrict__ x_in)
{
  int idx = blockIdx.x * 256 + threadIdx.x;        // 2048*128
  int i = idx >> 7, c = idx & 127;
  float zs = zb[i * 128 + c] + zb[(i + B2) * 128 + c] + bnn[c];
  x_in[i * 128 + c]        = fmaxf(aggA[idx] + zs, 0.f);
  x_in[(i + B2) * 128 + c] = fmaxf(aggB[idx] + zs, 0.f);
}

// GRU elementwise
__global__ __launch_bounds__(256) void gru_kernel(
    const float* __restrict__ gi, const float* __restrict__ gh,
    const float* __restrict__ xp, float* __restrict__ xnew)
{
  int idx = blockIdx.x * 256 + threadIdx.x;        // 4096*128
  int n = idx >> 7, j = idx & 127;
  float ir = gi[n * 384 + j], iz = gi[n * 384 + 128 + j], ih = gi[n * 384 + 256 + j];
  float hr = gh[n * 384 + j], hz = gh[n * 384 + 128 + j], hn = gh[n * 384 + 256 + j];
  float h  = xp[idx];
  float r  = 1.f / (1.f + expf(-(ir + hr)));
  float zg = 1.f / (1.f + expf(-(iz + hz)));
  float ng = tanhf(ih + r * hn);
  xnew[idx] = (1.f - zg) * ng + zg * h;
}

// out = o2 @ Wcl3 + bcl3   (N=2)
__global__ __launch_bounds__(256) void final_kernel(
    const float* __restrict__ o2, const float* __restrict__ Wcl3,
    const float* __restrict__ bcl3, float* __restrict__ out)
{
  int idx = blockIdx.x * 256 + threadIdx.x;        // 2048*2
  int i = idx >> 1, c = idx & 1;
  float acc = bcl3[c];
  for (int k = 0; k < 128; ++k) acc = fmaf(o2[i * 128 + k], Wcl3[k * 2 + c], acc);
  out[idx] = acc;
}

// ---------------------------------------------------------------------------
extern "C" void kernel_launch(void* const* d_in, const int* in_sizes, int n_in,
                              void* d_out, int out_size, void* d_ws, size_t ws_size,
                              hipStream_t stream)
{
  const float* h1   = (const float*)d_in[0];
  const float* h2   = (const float*)d_in[1];
  const float* s1x  = (const float*)d_in[2];
  const float* ihb  = (const float*)d_in[3];
  const float* ia1  = (const float*)d_in[4];
  const float* ia2  = (const float*)d_in[5];
  const float* Wg1  = (const float*)d_in[6];
  const float* bg1  = (const float*)d_in[7];
  const float* Wg2  = (const float*)d_in[8];
  const float* bg2  = (const float*)d_in[9];
  const float* Wp   = (const float*)d_in[10];
  const float* bp   = (const float*)d_in[11];
  const float* We1  = (const float*)d_in[12];
  const float* be1  = (const float*)d_in[13];
  const float* We2  = (const float*)d_in[14];
  const float* be2  = (const float*)d_in[15];
  const float* bnn  = (const float*)d_in[16];
  const float* Wih  = (const float*)d_in[17];
  const float* bih  = (const float*)d_in[18];
  const float* Whh  = (const float*)d_in[19];
  const float* bhh  = (const float*)d_in[20];
  const float* Wcl1 = (const float*)d_in[21];
  const float* bcl1 = (const float*)d_in[22];
  const float* Wcl2 = (const float*)d_in[23];
  const float* bcl2 = (const float*)d_in[24];
  const float* Wcl3 = (const float*)d_in[25];
  const float* bcl3 = (const float*)d_in[26];
  const int*   src1 = (const int*)d_in[27];
  const int*   dst1 = (const int*)d_in[28];
  const int*   src2 = (const int*)d_in[29];
  const int*   dst2 = (const int*)d_in[30];
  float* out = (float*)d_out;

  float* ws = (float*)d_ws;
  float* xcat = ws;                    // 4096*128
  float* xp   = ws + 524288;           // 4096*128
  float* zb   = ws + 1048576;          // 4096*128
  float* aggA = ws + 1572864;          // 2048*128
  float* aggB = ws + 1835008;          // 2048*128
  float* x_in = ws + 2097152;          // 4096*128
  float* gi   = ws + 2621440;          // 4096*384
  float* gh   = ws + 4194304;          // 4096*384
  float* xnew = ws + 5767168;          // 4096*128
  float* o1   = ws + 6291456;          // 2048*128
  float* o2   = ws + 6553600;          // 2048*128

  // GraphConv x2, both graphs, mean pool -> xcat (4096x128)
  gc_kernel<<<4096, 256, 0, stream>>>(h1, h2, src1, dst1, src2, dst2,
                                      Wg1, bg1, Wg2, bg2, s1x, xcat);
  // xp = relu(xcat @ Wp + bp)
  gemm_kernel<1, 1><<<dim3(64, 2), 256, 0, stream>>>(xcat, Wp, bp, xp, 4096, 128, 128);
  // zb = xp @ reshape(be2, (128,128))
  gemm_kernel<0, 0><<<dim3(64, 2), 256, 0, stream>>>(xp, be2, nullptr, zb, 4096, 128, 128);
  // zero agg accumulators, then fused z-fold (eh computed inline)
  hipMemsetAsync(aggA, 0, 2 * 262144 * sizeof(float), stream);
  zfold_kernel<<<256, 256, 0, stream>>>(xp, We2, ihb, ia1, ia2, We1, be1, aggA, aggB);
  xin_kernel<<<1024, 256, 0, stream>>>(aggA, aggB, zb, bnn, x_in);
  // GRU
  gemm_kernel<0, 1><<<dim3(64, 6), 256, 0, stream>>>(x_in, Wih, bih, gi, 4096, 384, 128);
  gemm_kernel<0, 1><<<dim3(64, 6), 256, 0, stream>>>(xp, Whh, bhh, gh, 4096, 384, 128);
  gru_kernel<<<2048, 256, 0, stream>>>(gi, gh, xp, xnew);
  // classifier (concat fused into first GEMM)
  gemm_cat_kernel<<<dim3(32, 2), 256, 0, stream>>>(xnew, Wcl1, bcl1, o1);
  gemm_kernel<1, 1><<<dim3(32, 2), 256, 0, stream>>>(o1, Wcl2, bcl2, o2, 2048, 128, 128);
  final_kernel<<<16, 256, 0, stream>>>(o2, Wcl3, bcl3, out);
}